// Round 1
// baseline (559.427 us; speedup 1.0000x reference)
//
#include <hip/hip_runtime.h>
#include <cstdint>
#include <cstddef>

#define EDGES 800000
#define NODES 50000

typedef short bf16x8 __attribute__((ext_vector_type(8)));
typedef float f32x4 __attribute__((ext_vector_type(4)));

__device__ __forceinline__ short f2bf(float v) {
  uint32_t u = __builtin_bit_cast(uint32_t, v);
  u = (u + 0x7FFFu + ((u >> 16) & 1u)) >> 16;
  return (short)u;
}

__device__ __forceinline__ float silu_f(float v) {
  return v * (1.0f / (1.0f + __expf(-v)));
}

// Stage Wt[col][k] = Weff[k][col] as bf16 into LDS, XOR-swizzled.
// Weff rows 0..127 = W1 rows 0..127 ; rows 128..159 = W_e2 @ W1[128:160,:]
// (edge-MLP second linear folded into the main GEMM).
__device__ __forceinline__ void stage_weights(short* lds, const float* __restrict__ W1,
                                              const float* __restrict__ We2) {
  const int t = (int)threadIdx.x;  // 256 threads
  const int col = t >> 1;          // 0..127
  const int kb = (t & 1) * 80;     // k range split
  float wcol[32];
#pragma unroll
  for (int cc = 0; cc < 32; ++cc) wcol[cc] = W1[(128 + cc) * 128 + col];
#pragma unroll
  for (int ch = 0; ch < 10; ++ch) {
    const int koff = kb + ch * 8;
    bf16x8 v;
#pragma unroll
    for (int j = 0; j < 8; ++j) {
      const int k = koff + j;
      float val;
      if (k < 128) {
        val = W1[k * 128 + col];
      } else {
        float s = 0.f;
#pragma unroll
        for (int cc = 0; cc < 32; ++cc) s = fmaf(We2[(k - 128) * 32 + cc], wcol[cc], s);
        val = s;
      }
      v[j] = f2bf(val);
    }
    const int swz = (koff < 128) ? ((col & 7) << 3) : ((col & 3) << 3);
    *(bf16x8*)&lds[col * 160 + (koff ^ swz)] = v;
  }
}

__global__ void k_init(const float* __restrict__ h, const float* __restrict__ x,
                       float* __restrict__ out) {
  const int i = (int)(blockIdx.x * 256 + threadIdx.x);
  if (i < 800000) {
    ((f32x4*)out)[i] = ((const f32x4*)h)[i];
  } else if (i < 837500) {
    ((f32x4*)out)[i] = ((const f32x4*)x)[i - 800000];
  }
}

__global__ __launch_bounds__(256, 2) void k_node(
    const float* __restrict__ h, const float* __restrict__ edist,
    const float* __restrict__ We1, const float* __restrict__ be1,
    const float* __restrict__ We2, const float* __restrict__ be2,
    const float* __restrict__ Wn1, const float* __restrict__ bn1,
    const float* __restrict__ Wn2, const float* __restrict__ bn2,
    const int* __restrict__ eidx, float* __restrict__ out) {
  __shared__ __align__(16) short ldsw[128 * 160];
  __shared__ __align__(16) short scr[4][16 * 136];
  stage_weights(ldsw, Wn1, We2);
  __syncthreads();

  const int tid = (int)threadIdx.x;
  const int w = tid >> 6, l = tid & 63, g = l >> 4, c = l & 15;
  short* myscr = &scr[w][0];

  float we1s[8], be1s[8];
#pragma unroll
  for (int j = 0; j < 8; ++j) { we1s[j] = We1[g * 8 + j]; be1s[j] = be1[g * 8 + j]; }

  // effective bias for layer 1: b_n1 + b_e2 @ W_n1[128:160,:]
  float bias1[8];
#pragma unroll
  for (int nt = 0; nt < 8; ++nt) {
    const int colf = nt * 16 + c;
    float s = bn1[colf];
    for (int cc = 0; cc < 32; ++cc) s = fmaf(be2[cc], Wn1[(128 + cc) * 128 + colf], s);
    bias1[nt] = s;
  }
  float bias2[4];
#pragma unroll
  for (int nt = 0; nt < 4; ++nt) bias2[nt] = bn2[nt * 16 + c];

  // W_n2 B-fragments kept in registers: [nt_out][kt]
  bf16x8 wf[4][4];
#pragma unroll
  for (int nt = 0; nt < 4; ++nt)
#pragma unroll
    for (int kt = 0; kt < 4; ++kt) {
      bf16x8 v;
#pragma unroll
      for (int j = 0; j < 8; ++j) v[j] = f2bf(Wn2[(kt * 32 + g * 8 + j) * 64 + nt * 16 + c]);
      wf[nt][kt] = v;
    }

  const f32x4 vzero = {0.f, 0.f, 0.f, 0.f};

  for (int t = (int)blockIdx.x; t < EDGES / 128; t += (int)gridDim.x) {
    const int base = t * 128 + w * 32;
    const int e0 = base + c, e1 = base + 16 + c;
    const int s0 = eidx[e0], s1 = eidx[e1];
    const int d0 = eidx[EDGES + e0], d1 = eidx[EDGES + e1];
    const float dd0 = edist[e0], dd1 = edist[e1];

    f32x4 acc[2][8];
#pragma unroll
    for (int mt = 0; mt < 2; ++mt)
#pragma unroll
      for (int nt = 0; nt < 8; ++nt) acc[mt][nt] = vzero;

#pragma unroll
    for (int kt = 0; kt < 5; ++kt) {
      bf16x8 a0, a1;
      if (kt < 4) {
        const float* r0 = h + (size_t)((kt < 2) ? s0 : d0) * 64;
        const float* r1 = h + (size_t)((kt < 2) ? s1 : d1) * 64;
        const int off = (kt & 1) * 32 + g * 8;
        const f32x4 pa = *(const f32x4*)(r0 + off);
        const f32x4 pb = *(const f32x4*)(r0 + off + 4);
        const f32x4 qa = *(const f32x4*)(r1 + off);
        const f32x4 qb = *(const f32x4*)(r1 + off + 4);
#pragma unroll
        for (int j = 0; j < 4; ++j) {
          a0[j] = f2bf(pa[j]); a0[4 + j] = f2bf(pb[j]);
          a1[j] = f2bf(qa[j]); a1[4 + j] = f2bf(qb[j]);
        }
      } else {
#pragma unroll
        for (int j = 0; j < 8; ++j) {
          a0[j] = f2bf(silu_f(fmaf(dd0, we1s[j], be1s[j])));
          a1[j] = f2bf(silu_f(fmaf(dd1, we1s[j], be1s[j])));
        }
      }
      const int koff = kt * 32 + g * 8;
      const int swz = (kt < 4) ? ((c & 7) << 3) : ((c & 3) << 3);
#pragma unroll
      for (int nt = 0; nt < 8; ++nt) {
        const bf16x8 b = *(const bf16x8*)&ldsw[(nt * 16 + c) * 160 + (koff ^ swz)];
        acc[0][nt] = __builtin_amdgcn_mfma_f32_16x16x32_bf16(a0, b, acc[0][nt], 0, 0, 0);
        acc[1][nt] = __builtin_amdgcn_mfma_f32_16x16x32_bf16(a1, b, acc[1][nt], 0, 0, 0);
      }
    }

#pragma unroll
    for (int mt = 0; mt < 2; ++mt) {
      // silu + bias -> bf16 scratch (wave-private, row = edge, col = hid feat)
#pragma unroll
      for (int nt = 0; nt < 8; ++nt)
#pragma unroll
        for (int r = 0; r < 4; ++r)
          myscr[(g * 4 + r) * 136 + nt * 16 + c] = f2bf(silu_f(acc[mt][nt][r] + bias1[nt]));

      f32x4 acc2[4];
#pragma unroll
      for (int nt = 0; nt < 4; ++nt) acc2[nt] = vzero;
#pragma unroll
      for (int kt = 0; kt < 4; ++kt) {
        const bf16x8 a2 = *(const bf16x8*)&myscr[c * 136 + kt * 32 + g * 8];
#pragma unroll
        for (int nt = 0; nt < 4; ++nt)
          acc2[nt] = __builtin_amdgcn_mfma_f32_16x16x32_bf16(a2, wf[nt][kt], acc2[nt], 0, 0, 0);
      }
      const int dstm = mt ? d1 : d0;
#pragma unroll
      for (int r = 0; r < 4; ++r) {
        const int de = __shfl(dstm, g * 4 + r);
#pragma unroll
        for (int nt = 0; nt < 4; ++nt)
          unsafeAtomicAdd(&out[de * 64 + nt * 16 + c], acc2[nt][r] + bias2[nt]);
      }
    }
  }
}

__global__ __launch_bounds__(256, 2) void k_coord(
    const float* __restrict__ h, const float* __restrict__ x,
    const float* __restrict__ edist,
    const float* __restrict__ We1, const float* __restrict__ be1,
    const float* __restrict__ We2, const float* __restrict__ be2,
    const float* __restrict__ Wc1, const float* __restrict__ bc1,
    const float* __restrict__ Wc2,
    const int* __restrict__ eidx, float* __restrict__ xo) {
  __shared__ __align__(16) short ldsw[128 * 160];
  stage_weights(ldsw, Wc1, We2);
  __syncthreads();

  const int tid = (int)threadIdx.x;
  const int w = tid >> 6, l = tid & 63, g = l >> 4, c = l & 15;

  float we1s[8], be1s[8];
#pragma unroll
  for (int j = 0; j < 8; ++j) { we1s[j] = We1[g * 8 + j]; be1s[j] = be1[g * 8 + j]; }

  float bias1[8], wc2l[8];
#pragma unroll
  for (int nt = 0; nt < 8; ++nt) {
    const int colf = nt * 16 + c;
    float s = bc1[colf];
    for (int cc = 0; cc < 32; ++cc) s = fmaf(be2[cc], Wc1[(128 + cc) * 128 + colf], s);
    bias1[nt] = s;
    wc2l[nt] = Wc2[colf];
  }

  const f32x4 vzero = {0.f, 0.f, 0.f, 0.f};

  for (int t = (int)blockIdx.x; t < EDGES / 128; t += (int)gridDim.x) {
    const int base = t * 128 + w * 32;
    const int e0 = base + c, e1 = base + 16 + c;
    const int s0 = eidx[e0], s1 = eidx[e1];
    const int d0 = eidx[EDGES + e0], d1 = eidx[EDGES + e1];
    const float dd0 = edist[e0], dd1 = edist[e1];

    f32x4 acc[2][8];
#pragma unroll
    for (int mt = 0; mt < 2; ++mt)
#pragma unroll
      for (int nt = 0; nt < 8; ++nt) acc[mt][nt] = vzero;

#pragma unroll
    for (int kt = 0; kt < 5; ++kt) {
      bf16x8 a0, a1;
      if (kt < 4) {
        const float* r0 = h + (size_t)((kt < 2) ? s0 : d0) * 64;
        const float* r1 = h + (size_t)((kt < 2) ? s1 : d1) * 64;
        const int off = (kt & 1) * 32 + g * 8;
        const f32x4 pa = *(const f32x4*)(r0 + off);
        const f32x4 pb = *(const f32x4*)(r0 + off + 4);
        const f32x4 qa = *(const f32x4*)(r1 + off);
        const f32x4 qb = *(const f32x4*)(r1 + off + 4);
#pragma unroll
        for (int j = 0; j < 4; ++j) {
          a0[j] = f2bf(pa[j]); a0[4 + j] = f2bf(pb[j]);
          a1[j] = f2bf(qa[j]); a1[4 + j] = f2bf(qb[j]);
        }
      } else {
#pragma unroll
        for (int j = 0; j < 8; ++j) {
          a0[j] = f2bf(silu_f(fmaf(dd0, we1s[j], be1s[j])));
          a1[j] = f2bf(silu_f(fmaf(dd1, we1s[j], be1s[j])));
        }
      }
      const int koff = kt * 32 + g * 8;
      const int swz = (kt < 4) ? ((c & 7) << 3) : ((c & 3) << 3);
#pragma unroll
      for (int nt = 0; nt < 8; ++nt) {
        const bf16x8 b = *(const bf16x8*)&ldsw[(nt * 16 + c) * 160 + (koff ^ swz)];
        acc[0][nt] = __builtin_amdgcn_mfma_f32_16x16x32_bf16(a0, b, acc[0][nt], 0, 0, 0);
        acc[1][nt] = __builtin_amdgcn_mfma_f32_16x16x32_bf16(a1, b, acc[1][nt], 0, 0, 0);
      }
    }

#pragma unroll
    for (int mt = 0; mt < 2; ++mt) {
      // coord_w = silu(hid) . W_c2 : per-lane partial over its 8 cols, then
      // butterfly-reduce across the 16 lanes of each group.
      float p[4] = {0.f, 0.f, 0.f, 0.f};
#pragma unroll
      for (int nt = 0; nt < 8; ++nt)
#pragma unroll
        for (int r = 0; r < 4; ++r)
          p[r] += silu_f(acc[mt][nt][r] + bias1[nt]) * wc2l[nt];
#pragma unroll
      for (int m = 1; m < 16; m <<= 1)
#pragma unroll
        for (int r = 0; r < 4; ++r) p[r] += __shfl_xor(p[r], m);

      const int srcm = mt ? s1 : s0;
      const int dstm = mt ? d1 : d0;
      const int el = (g * 4 + c) & 15;
      const int se = __shfl(srcm, el);
      const int de = __shfl(dstm, el);
      const float cw = (c == 0) ? p[0] : (c == 1) ? p[1] : (c == 2) ? p[2] : p[3];
      if (c < 4) {
        const float ax = x[se * 3 + 0] - x[de * 3 + 0];
        const float ay = x[se * 3 + 1] - x[de * 3 + 1];
        const float az = x[se * 3 + 2] - x[de * 3 + 2];
        float len = sqrtf(fmaf(ax, ax, fmaf(ay, ay, az * az)));
        len = fmaxf(len, 1e-8f);
        const float scl = cw / len;
        unsafeAtomicAdd(&xo[de * 3 + 0], scl * ax);
        unsafeAtomicAdd(&xo[de * 3 + 1], scl * ay);
        unsafeAtomicAdd(&xo[de * 3 + 2], scl * az);
      }
    }
  }
}

extern "C" void kernel_launch(void* const* d_in, const int* in_sizes, int n_in,
                              void* d_out, int out_size, void* d_ws, size_t ws_size,
                              hipStream_t stream) {
  const float* h = (const float*)d_in[0];
  const float* x = (const float*)d_in[1];
  const float* edist = (const float*)d_in[2];
  const float* We1 = (const float*)d_in[3];
  const float* be1 = (const float*)d_in[4];
  const float* We2 = (const float*)d_in[5];
  const float* be2 = (const float*)d_in[6];
  const float* Wn1 = (const float*)d_in[7];
  const float* bn1 = (const float*)d_in[8];
  const float* Wn2 = (const float*)d_in[9];
  const float* bn2 = (const float*)d_in[10];
  const float* Wc1 = (const float*)d_in[11];
  const float* bc1 = (const float*)d_in[12];
  const float* Wc2 = (const float*)d_in[13];
  const int* eidx = (const int*)d_in[14];
  float* out = (float*)d_out;
  float* xo = out + 3200000;

  k_init<<<dim3(3272), dim3(256), 0, stream>>>(h, x, out);
  k_node<<<dim3(512), dim3(256), 0, stream>>>(h, edist, We1, be1, We2, be2, Wn1, bn1,
                                              Wn2, bn2, eidx, out);
  k_coord<<<dim3(512), dim3(256), 0, stream>>>(h, x, edist, We1, be1, We2, be2, Wc1,
                                               bc1, Wc2, eidx, xo);
}